// Round 1
// baseline (144.898 us; speedup 1.0000x reference)
//
#include <hip/hip_runtime.h>

#define TSTEPS 256
#define NOBJ   8192
#define BATCH  64
#define DEMB   32
#define DATT   128

__device__ __forceinline__ int load_t(const void* p) {
    // t is a 1-element scalar array; most likely int32 (value 8).
    unsigned w0 = *(const unsigned*)p;
    if (w0 < (unsigned)TSTEPS) return (int)w0;          // int32 / low word of small int64
    float f = __uint_as_float(w0);
    if (f >= 0.f && f < 256.f) return (int)f;           // float32
    return 8;
}

__device__ __forceinline__ float fast_tanh(float x) {
    // tanh(x) = 1 - 2/(exp(2x)+1); saturates correctly for |x| large.
    float e = __expf(2.0f * x);
    return 1.0f - 2.0f / (e + 1.0f);
}

__device__ __forceinline__ int lower_bound(const int* a, int n, int v) {
    int lo = 0, hi = n;
    while (lo < hi) { int mid = (lo + hi) >> 1; if (a[mid] < v) lo = mid + 1; else hi = mid; }
    return lo;
}

struct K1P {
    const float* x[5]; const int* cls[5]; const int* seg[5];
    const float* W[5]; const float* bias[5];
    const float* h_ped; const float* Wax; const float* Wah; const float* ba; const float* va;
    const int* t_ptr;
    float* out;
    int d[5];
};

// One block per (type, segment b). 5*64 = 320 blocks, 256 threads.
__global__ __launch_bounds__(256) void k_attend(K1P p) {
    const int type = blockIdx.x >> 6;
    const int bseg = blockIdx.x & 63;
    const int tid  = threadIdx.x;
    const int d    = p.d[type];
    const int t    = load_t(p.t_ptr);
    const float* __restrict__ x   = p.x[type];
    const int*   __restrict__ cls = p.cls[type];
    const int*   __restrict__ seg = p.seg[type];

    __shared__ __align__(16) float WaxT[DATT * DEMB];  // WaxT[j*32+k] = Wax[k*128+j]
    __shared__ float W_s[7 * DEMB];
    __shared__ float b_s[DEMB];
    __shared__ float va_s[DATT];
    __shared__ float hW[DATT];
    __shared__ float mred[4], sred[4];
    __shared__ float accred[4][DEMB];

    for (int i = tid; i < DEMB * DATT; i += 256) {
        int j = i >> 5, k = i & 31;
        WaxT[i] = p.Wax[k * DATT + j];
    }
    for (int i = tid; i < d * DEMB; i += 256) W_s[i] = p.W[type][i];
    if (tid < DEMB) b_s[tid] = p.bias[type][tid];
    if (tid < DATT) va_s[tid] = p.va[tid];
    if (tid >= 128 && tid < 256) {
        int j = tid - 128;
        float a = p.ba[j];
        const float* h = p.h_ped + bseg * DEMB;
        for (int k = 0; k < DEMB; ++k) a += h[k] * p.Wah[k * DATT + j];
        hW[j] = a;
    }
    const int lo = lower_bound(seg, NOBJ, bseg);
    const int hi = lower_bound(seg, NOBJ, bseg + 1);
    __syncthreads();

    auto compute = [&](int i, float emb[DEMB]) -> float {
        float xv[7];
        const float* xr = x + (size_t)(i * TSTEPS + t) * d;
        for (int k = 0; k < d; ++k) xv[k] = xr[k];
        #pragma unroll
        for (int j = 0; j < DEMB; ++j) {
            float a = b_s[j];
            for (int k = 0; k < d; ++k) a += xv[k] * W_s[k * DEMB + j];
            emb[j] = fmaxf(a, 0.f);
        }
        float sc = 0.f;
        #pragma unroll 4
        for (int j = 0; j < DATT; ++j) {
            float a = hW[j];
            const float4* wr = (const float4*)&WaxT[j * DEMB];
            #pragma unroll
            for (int k4 = 0; k4 < DEMB / 4; ++k4) {
                float4 w = wr[k4];
                a += emb[4*k4+0]*w.x + emb[4*k4+1]*w.y + emb[4*k4+2]*w.z + emb[4*k4+3]*w.w;
            }
            sc += fast_tanh(a) * va_s[j];
        }
        return sc;
    };

    // pass 1: online (max, sum-exp) over valid objects of this segment
    float m = -1e30f, s = 0.f;
    for (int i = lo + tid; i < hi; i += 256) {
        if (cls[i * TSTEPS + t] == -1) continue;
        float emb[DEMB];
        float sc = compute(i, emb);
        float M = fmaxf(m, sc);
        s = s * __expf(m - M) + __expf(sc - M);
        m = M;
    }
    #pragma unroll
    for (int off = 32; off; off >>= 1) {
        float m2 = __shfl_xor(m, off);
        float s2 = __shfl_xor(s, off);
        float M = fmaxf(m, m2);
        s = s * __expf(m - M) + s2 * __expf(m2 - M);
        m = M;
    }
    const int wave = tid >> 6;
    if ((tid & 63) == 0) { mred[wave] = m; sred[wave] = s; }
    __syncthreads();
    const float Mf = fmaxf(fmaxf(mred[0], mred[1]), fmaxf(mred[2], mred[3]));
    float Sf = sred[0] * __expf(mred[0] - Mf) + sred[1] * __expf(mred[1] - Mf)
             + sred[2] * __expf(mred[2] - Mf) + sred[3] * __expf(mred[3] - Mf);
    Sf = fmaxf(Sf, 1e-30f);

    // pass 2: probs + weighted feature sum
    float acc[DEMB];
    #pragma unroll
    for (int j = 0; j < DEMB; ++j) acc[j] = 0.f;
    float* pout = p.out + 64 + BATCH * 224 + type * NOBJ;
    for (int i = lo + tid; i < hi; i += 256) {
        float pr = 0.f;
        if (cls[i * TSTEPS + t] != -1) {
            float emb[DEMB];
            float sc = compute(i, emb);
            pr = __expf(sc - Mf) / Sf;
            #pragma unroll
            for (int j = 0; j < DEMB; ++j) acc[j] += pr * emb[j];
        }
        pout[i] = pr;
    }
    #pragma unroll
    for (int j = 0; j < DEMB; ++j)
        for (int off = 32; off; off >>= 1)
            acc[j] += __shfl_xor(acc[j], off);
    if ((tid & 63) == 0)
        for (int j = 0; j < DEMB; ++j) accred[wave][j] = acc[j];
    __syncthreads();
    if (tid < DEMB) {
        float f = accred[0][tid] + accred[1][tid] + accred[2][tid] + accred[3][tid];
        p.out[64 + bseg * 224 + 32 * (1 + type) + tid] = f;
    }
}

struct K2P {
    const float* x_ped; const float* x_ego;
    const float* Wp; const float* bp; const float* We; const float* be;
    const float* W1; const float* b1; const float* W2; const float* b2;
    const float* W3; const float* b3;
    const int* t_ptr;
    float* out;
};

// Single block: ped/ego embeddings + classifier head.
__global__ __launch_bounds__(256) void k_head(K2P p) {
    const int tid = threadIdx.x;
    const int t = load_t(p.t_ptr);
    __shared__ float F[BATCH][224];
    __shared__ float H1[BATCH][DEMB];
    __shared__ float H2[BATCH][DEMB];
    __shared__ float Wp_s[4 * DEMB], We_s[4 * DEMB];
    __shared__ float W2_s[DEMB * DEMB];
    __shared__ float bp_s[DEMB], be_s[DEMB], b1_s[DEMB], b2_s[DEMB], W3_s[DEMB];

    float* feats_out = p.out + 64;

    for (int i = tid; i < 4 * DEMB; i += 256) { Wp_s[i] = p.Wp[i]; We_s[i] = p.We[i]; }
    for (int i = tid; i < DEMB * DEMB; i += 256) W2_s[i] = p.W2[i];
    if (tid < DEMB) {
        bp_s[tid] = p.bp[tid]; be_s[tid] = p.be[tid];
        b1_s[tid] = p.b1[tid]; b2_s[tid] = p.b2[tid];
        W3_s[tid] = p.W3[tid];
    }
    __syncthreads();

    // ped (cols 0..31) and ego (cols 192..223)
    for (int idx = tid; idx < BATCH * DEMB; idx += 256) {
        int b = idx >> 5, j = idx & 31;
        const float* xp = p.x_ped + (size_t)(b * TSTEPS + t) * 4;
        float a = bp_s[j];
        #pragma unroll
        for (int k = 0; k < 4; ++k) a += xp[k] * Wp_s[k * DEMB + j];
        a = fmaxf(a, 0.f);
        F[b][j] = a;
        feats_out[b * 224 + j] = a;
        const float* xe = p.x_ego + (size_t)(b * TSTEPS + t) * 4;
        float e = be_s[j];
        #pragma unroll
        for (int k = 0; k < 4; ++k) e += xe[k] * We_s[k * DEMB + j];
        e = fmaxf(e, 0.f);
        F[b][192 + j] = e;
        feats_out[b * 224 + 192 + j] = e;
    }
    // middle cols 32..191 from kernel 1's output
    for (int idx = tid; idx < BATCH * 160; idx += 256) {
        int b = idx / 160, c = idx - b * 160;
        F[b][32 + c] = feats_out[b * 224 + 32 + c];
    }
    __syncthreads();

    // h1 = relu(F @ W1 + b1)
    for (int idx = tid; idx < BATCH * DEMB; idx += 256) {
        int b = idx >> 5, j = idx & 31;
        float a = b1_s[j];
        for (int k = 0; k < 224; ++k) a += F[b][k] * p.W1[k * DEMB + j];
        H1[b][j] = fmaxf(a, 0.f);
    }
    __syncthreads();
    // h2 = relu(H1 @ W2 + b2)
    for (int idx = tid; idx < BATCH * DEMB; idx += 256) {
        int b = idx >> 5, j = idx & 31;
        float a = b2_s[j];
        #pragma unroll
        for (int k = 0; k < DEMB; ++k) a += H1[b][k] * W2_s[k * DEMB + j];
        H2[b][j] = fmaxf(a, 0.f);
    }
    __syncthreads();
    // out = H2 @ W3 + b3
    if (tid < BATCH) {
        float a = p.b3[0];
        #pragma unroll
        for (int k = 0; k < DEMB; ++k) a += H2[tid][k] * W3_s[k];
        p.out[tid] = a;
    }
}

extern "C" void kernel_launch(void* const* d_in, const int* in_sizes, int n_in,
                              void* d_out, int out_size, void* d_ws, size_t ws_size,
                              hipStream_t stream) {
    (void)in_sizes; (void)n_in; (void)d_ws; (void)ws_size; (void)out_size;

    K1P p1;
    const int xi[5] = {3, 6, 9, 12, 15};    // x_{neighbor,light,sign,crosswalk,station}
    const int wi[5] = {20, 22, 24, 26, 28}; // Wn, Wl, Wsi, Wc, Wst
    const int di[5] = {4, 6, 5, 7, 7};
    for (int tp = 0; tp < 5; ++tp) {
        p1.x[tp]    = (const float*)d_in[xi[tp]];
        p1.cls[tp]  = (const int*)d_in[xi[tp] + 1];
        p1.seg[tp]  = (const int*)d_in[xi[tp] + 2];
        p1.W[tp]    = (const float*)d_in[wi[tp]];
        p1.bias[tp] = (const float*)d_in[wi[tp] + 1];
        p1.d[tp]    = di[tp];
    }
    p1.h_ped = (const float*)d_in[2];
    p1.Wax   = (const float*)d_in[32];
    p1.Wah   = (const float*)d_in[33];
    p1.ba    = (const float*)d_in[34];
    p1.va    = (const float*)d_in[35];
    p1.t_ptr = (const int*)d_in[42];
    p1.out   = (float*)d_out;
    hipLaunchKernelGGL(k_attend, dim3(5 * BATCH), dim3(256), 0, stream, p1);

    K2P p2;
    p2.x_ped = (const float*)d_in[0];
    p2.x_ego = (const float*)d_in[1];
    p2.Wp = (const float*)d_in[18]; p2.bp = (const float*)d_in[19];
    p2.We = (const float*)d_in[30]; p2.be = (const float*)d_in[31];
    p2.W1 = (const float*)d_in[36]; p2.b1 = (const float*)d_in[37];
    p2.W2 = (const float*)d_in[38]; p2.b2 = (const float*)d_in[39];
    p2.W3 = (const float*)d_in[40]; p2.b3 = (const float*)d_in[41];
    p2.t_ptr = (const int*)d_in[42];
    p2.out = (float*)d_out;
    hipLaunchKernelGGL(k_head, dim3(1), dim3(256), 0, stream, p2);
}

// Round 2
// 87.422 us; speedup vs baseline: 1.6574x; 1.6574x over previous
//
#include <hip/hip_runtime.h>

#define TSTEPS 256
#define NOBJ   8192
#define BATCH  64
#define DEMB   32
#define DATT   128
#define OBJ_PER_BLK 32

struct SP {
    const float* x[5]; const int* cls[5]; const int* seg[5];
    const float* W[5]; const float* bias[5];
    const float* x_ped; const float* x_ego; const float* h_ped;
    const float* Wp; const float* bp; const float* We; const float* be;
    const float* Wax; const float* Wah; const float* ba; const float* va;
    const float* W1; const float* b1; const float* W2; const float* b2;
    const float* W3; const float* b3;
    const int* t_ptr;
    float* out;
    float* hW;      // ws: [64][128]
    float* scores;  // ws: [5][8192]
    int d[5];
};

__device__ __forceinline__ int load_t(const void* p) {
    unsigned w0 = *(const unsigned*)p;
    if (w0 < (unsigned)TSTEPS) return (int)w0;
    float f = __uint_as_float(w0);
    if (f >= 0.f && f < 256.f) return (int)f;
    return 8;
}

__device__ __forceinline__ float fast_tanh(float x) {
    float e = __expf(2.0f * x);
    return 1.0f - 2.0f / (e + 1.0f);
}

__device__ __forceinline__ int lower_bound(const int* a, int n, int v) {
    int lo = 0, hi = n;
    while (lo < hi) { int mid = (lo + hi) >> 1; if (a[mid] < v) lo = mid + 1; else hi = mid; }
    return lo;
}

// ---- kernel 0: hW[b][j] = ba[j] + h_ped[b] @ Wah[:,j]; plus ped/ego embeddings
__global__ __launch_bounds__(128) void k_prep(SP p) {
    const int b = blockIdx.x;
    const int j = threadIdx.x;
    const int t = load_t(p.t_ptr);
    float a = p.ba[j];
    const float* h = p.h_ped + b * DEMB;
    #pragma unroll
    for (int k = 0; k < DEMB; ++k) a += h[k] * p.Wah[k * DATT + j];
    p.hW[b * DATT + j] = a;

    if (j < DEMB) {
        const float* xp = p.x_ped + (size_t)(b * TSTEPS + t) * 4;
        float e = p.bp[j];
        #pragma unroll
        for (int k = 0; k < 4; ++k) e += xp[k] * p.Wp[k * DEMB + j];
        p.out[64 + b * 224 + j] = fmaxf(e, 0.f);
        const float* xe = p.x_ego + (size_t)(b * TSTEPS + t) * 4;
        float g = p.be[j];
        #pragma unroll
        for (int k = 0; k < 4; ++k) g += xe[k] * p.We[k * DEMB + j];
        p.out[64 + b * 224 + 192 + j] = fmaxf(g, 0.f);
    }
}

// ---- kernel 1: per-object attention score. 4 lanes per object.
__global__ __launch_bounds__(128) void k_score(SP p) {
    const int type = blockIdx.y;
    const int tid  = threadIdx.x;
    const int t    = load_t(p.t_ptr);
    const int d    = p.d[type];
    const float* __restrict__ x   = p.x[type];
    const int*   __restrict__ cls = p.cls[type];
    const int*   __restrict__ seg = p.seg[type];

    __shared__ __align__(16) float WaxT[DATT * DEMB];  // [j][k]
    __shared__ __align__(16) float W_s[7 * DEMB];
    __shared__ __align__(16) float b_s[DEMB];
    __shared__ __align__(16) float va_s[DATT];

    for (int i = tid; i < DATT * DEMB; i += 128) {
        int j = i >> 5, k = i & 31;
        WaxT[i] = p.Wax[k * DATT + j];
    }
    for (int i = tid; i < d * DEMB; i += 128) W_s[i] = p.W[type][i];
    if (tid < DEMB) b_s[tid] = p.bias[type][tid];
    va_s[tid] = p.va[tid];
    __syncthreads();

    const int i = blockIdx.x * OBJ_PER_BLK + (tid >> 2);
    const int q = tid & 3;
    if (cls[i * TSTEPS + t] == -1) return;   // group-uniform; no barriers after this
    const int b = seg[i];

    float xv[7];
    const float* xr = x + (size_t)(i * TSTEPS + t) * d;
    for (int k = 0; k < d; ++k) xv[k] = xr[k];

    float emb[DEMB];
    {
        const float4* W4 = (const float4*)W_s;
        const float4* b4 = (const float4*)b_s;
        #pragma unroll
        for (int j4 = 0; j4 < 8; ++j4) {
            float4 a = b4[j4];
            for (int k = 0; k < d; ++k) {
                float4 w = W4[k * 8 + j4];
                a.x += xv[k] * w.x; a.y += xv[k] * w.y;
                a.z += xv[k] * w.z; a.w += xv[k] * w.w;
            }
            emb[4*j4+0] = fmaxf(a.x, 0.f); emb[4*j4+1] = fmaxf(a.y, 0.f);
            emb[4*j4+2] = fmaxf(a.z, 0.f); emb[4*j4+3] = fmaxf(a.w, 0.f);
        }
    }

    float sc = 0.f;
    const float4* hw4 = (const float4*)(p.hW + b * DATT) + q * 8;
    const float4* va4 = (const float4*)va_s + q * 8;
    #pragma unroll
    for (int jo = 0; jo < 8; ++jo) {
        const int jj4 = (jo + 2 * q) & 7;        // rotate: bank-conflict-free across q
        float4 hw = hw4[jj4];
        float4 vv = va4[jj4];
        #pragma unroll
        for (int u = 0; u < 4; ++u) {
            const int j = q * 32 + jj4 * 4 + u;
            const float4* wr = (const float4*)&WaxT[j * DEMB];
            float a = (&hw.x)[u];
            #pragma unroll
            for (int co = 0; co < 8; ++co) {
                const int c = (co + 2 * q) & 7;  // banks = 4c, disjoint per q
                float4 w = wr[c];
                a += emb[4*c+0]*w.x + emb[4*c+1]*w.y + emb[4*c+2]*w.z + emb[4*c+3]*w.w;
            }
            sc += fast_tanh(a) * (&vv.x)[u];
        }
    }
    sc += __shfl_xor(sc, 1);
    sc += __shfl_xor(sc, 2);
    if (q == 0) p.scores[type * NOBJ + i] = sc;
}

// ---- kernel 2: segment softmax + weighted feature sum (emb recomputed, cheap)
__global__ __launch_bounds__(256) void k_softmax(SP p) {
    const int type = blockIdx.y;
    const int bseg = blockIdx.x;
    const int tid  = threadIdx.x;
    const int t    = load_t(p.t_ptr);
    const int d    = p.d[type];
    const float* __restrict__ x   = p.x[type];
    const int*   __restrict__ cls = p.cls[type];
    const int*   __restrict__ seg = p.seg[type];
    const float* __restrict__ scores = p.scores + type * NOBJ;

    __shared__ __align__(16) float W_s[7 * DEMB];
    __shared__ __align__(16) float b_s[DEMB];
    __shared__ float mred[4], sred[4];
    __shared__ float accred[4][DEMB];

    for (int i = tid; i < d * DEMB; i += 256) W_s[i] = p.W[type][i];
    if (tid < DEMB) b_s[tid] = p.bias[type][tid];
    const int lo = lower_bound(seg, NOBJ, bseg);
    const int hi = lower_bound(seg, NOBJ, bseg + 1);
    __syncthreads();

    float m = -1e30f, s = 0.f;
    for (int i = lo + tid; i < hi; i += 256) {
        if (cls[i * TSTEPS + t] == -1) continue;
        float sc = scores[i];
        float M = fmaxf(m, sc);
        s = s * __expf(m - M) + __expf(sc - M);
        m = M;
    }
    #pragma unroll
    for (int off = 32; off; off >>= 1) {
        float m2 = __shfl_xor(m, off);
        float s2 = __shfl_xor(s, off);
        float M = fmaxf(m, m2);
        s = s * __expf(m - M) + s2 * __expf(m2 - M);
        m = M;
    }
    const int wave = tid >> 6;
    if ((tid & 63) == 0) { mred[wave] = m; sred[wave] = s; }
    __syncthreads();
    const float Mf = fmaxf(fmaxf(mred[0], mred[1]), fmaxf(mred[2], mred[3]));
    float Sf = sred[0] * __expf(mred[0] - Mf) + sred[1] * __expf(mred[1] - Mf)
             + sred[2] * __expf(mred[2] - Mf) + sred[3] * __expf(mred[3] - Mf);
    Sf = fmaxf(Sf, 1e-30f);

    float acc[DEMB];
    #pragma unroll
    for (int j = 0; j < DEMB; ++j) acc[j] = 0.f;
    float* pout = p.out + 64 + BATCH * 224 + type * NOBJ;
    const float4* W4 = (const float4*)W_s;
    const float4* b4 = (const float4*)b_s;
    for (int i = lo + tid; i < hi; i += 256) {
        float pr = 0.f;
        if (cls[i * TSTEPS + t] != -1) {
            pr = __expf(scores[i] - Mf) / Sf;
            float xv[7];
            const float* xr = x + (size_t)(i * TSTEPS + t) * d;
            for (int k = 0; k < d; ++k) xv[k] = xr[k];
            #pragma unroll
            for (int j4 = 0; j4 < 8; ++j4) {
                float4 a = b4[j4];
                for (int k = 0; k < d; ++k) {
                    float4 w = W4[k * 8 + j4];
                    a.x += xv[k]*w.x; a.y += xv[k]*w.y; a.z += xv[k]*w.z; a.w += xv[k]*w.w;
                }
                acc[4*j4+0] += pr * fmaxf(a.x, 0.f);
                acc[4*j4+1] += pr * fmaxf(a.y, 0.f);
                acc[4*j4+2] += pr * fmaxf(a.z, 0.f);
                acc[4*j4+3] += pr * fmaxf(a.w, 0.f);
            }
        }
        pout[i] = pr;
    }
    #pragma unroll
    for (int j = 0; j < DEMB; ++j)
        #pragma unroll
        for (int off = 32; off; off >>= 1)
            acc[j] += __shfl_xor(acc[j], off);
    if ((tid & 63) == 0)
        for (int j = 0; j < DEMB; ++j) accred[wave][j] = acc[j];
    __syncthreads();
    if (tid < DEMB) {
        float f = accred[0][tid] + accred[1][tid] + accred[2][tid] + accred[3][tid];
        p.out[64 + bseg * 224 + 32 * (1 + type) + tid] = f;
    }
}

// ---- kernel 3: classifier head
__global__ __launch_bounds__(256) void k_head(SP p) {
    const int tid = threadIdx.x;
    __shared__ __align__(16) float W1_s[224 * DEMB];   // 28 KB
    __shared__ float W2_s[DEMB * DEMB];
    __shared__ float H1[BATCH][DEMB + 1];
    __shared__ float H2[BATCH][DEMB + 1];
    __shared__ float b1_s[DEMB], b2_s[DEMB], W3_s[DEMB];

    for (int i = tid; i < 224 * DEMB; i += 256) W1_s[i] = p.W1[i];
    for (int i = tid; i < DEMB * DEMB; i += 256) W2_s[i] = p.W2[i];
    if (tid < DEMB) { b1_s[tid] = p.b1[tid]; b2_s[tid] = p.b2[tid]; W3_s[tid] = p.W3[tid]; }
    __syncthreads();

    const float* feats = p.out + 64;
    for (int idx = tid; idx < BATCH * DEMB; idx += 256) {
        int b = idx >> 5, j = idx & 31;
        float a = b1_s[j];
        const float4* f4 = (const float4*)(feats + b * 224);
        #pragma unroll 8
        for (int k4 = 0; k4 < 56; ++k4) {
            float4 f = f4[k4];
            a += f.x * W1_s[(4*k4+0)*DEMB + j] + f.y * W1_s[(4*k4+1)*DEMB + j]
               + f.z * W1_s[(4*k4+2)*DEMB + j] + f.w * W1_s[(4*k4+3)*DEMB + j];
        }
        H1[b][j] = fmaxf(a, 0.f);
    }
    __syncthreads();
    for (int idx = tid; idx < BATCH * DEMB; idx += 256) {
        int b = idx >> 5, j = idx & 31;
        float a = b2_s[j];
        #pragma unroll
        for (int k = 0; k < DEMB; ++k) a += H1[b][k] * W2_s[k * DEMB + j];
        H2[b][j] = fmaxf(a, 0.f);
    }
    __syncthreads();
    if (tid < BATCH) {
        float a = p.b3[0];
        #pragma unroll
        for (int k = 0; k < DEMB; ++k) a += H2[tid][k] * W3_s[k];
        p.out[tid] = a;
    }
}

extern "C" void kernel_launch(void* const* d_in, const int* in_sizes, int n_in,
                              void* d_out, int out_size, void* d_ws, size_t ws_size,
                              hipStream_t stream) {
    (void)in_sizes; (void)n_in; (void)out_size; (void)ws_size;

    SP p;
    const int xi[5] = {3, 6, 9, 12, 15};
    const int wi[5] = {20, 22, 24, 26, 28};
    const int di[5] = {4, 6, 5, 7, 7};
    for (int tp = 0; tp < 5; ++tp) {
        p.x[tp]    = (const float*)d_in[xi[tp]];
        p.cls[tp]  = (const int*)d_in[xi[tp] + 1];
        p.seg[tp]  = (const int*)d_in[xi[tp] + 2];
        p.W[tp]    = (const float*)d_in[wi[tp]];
        p.bias[tp] = (const float*)d_in[wi[tp] + 1];
        p.d[tp]    = di[tp];
    }
    p.x_ped = (const float*)d_in[0];
    p.x_ego = (const float*)d_in[1];
    p.h_ped = (const float*)d_in[2];
    p.Wp = (const float*)d_in[18]; p.bp = (const float*)d_in[19];
    p.We = (const float*)d_in[30]; p.be = (const float*)d_in[31];
    p.Wax = (const float*)d_in[32]; p.Wah = (const float*)d_in[33];
    p.ba  = (const float*)d_in[34]; p.va  = (const float*)d_in[35];
    p.W1 = (const float*)d_in[36]; p.b1 = (const float*)d_in[37];
    p.W2 = (const float*)d_in[38]; p.b2 = (const float*)d_in[39];
    p.W3 = (const float*)d_in[40]; p.b3 = (const float*)d_in[41];
    p.t_ptr = (const int*)d_in[42];
    p.out = (float*)d_out;
    p.hW = (float*)d_ws;                                  // 32 KB
    p.scores = (float*)((char*)d_ws + BATCH * DATT * 4);  // 160 KB

    hipLaunchKernelGGL(k_prep,    dim3(BATCH),                    dim3(DATT), 0, stream, p);
    hipLaunchKernelGGL(k_score,   dim3(NOBJ / OBJ_PER_BLK, 5),    dim3(128),  0, stream, p);
    hipLaunchKernelGGL(k_softmax, dim3(BATCH, 5),                 dim3(256),  0, stream, p);
    hipLaunchKernelGGL(k_head,    dim3(1),                        dim3(256),  0, stream, p);
}

// Round 3
// 73.291 us; speedup vs baseline: 1.9770x; 1.1928x over previous
//
#include <hip/hip_runtime.h>

#define TSTEPS 256
#define NOBJ   8192
#define BATCH  64
#define DEMB   32
#define DATT   128
#define OPB    32   // objects per k_score block
#define LANES  8    // lanes per object

struct SP {
    const float* x[5]; const int* cls[5]; const int* seg[5];
    const float* W[5]; const float* bias[5];
    const float* x_ped; const float* x_ego; const float* h_ped;
    const float* Wp; const float* bp; const float* We; const float* be;
    const float* Wax; const float* Wah; const float* ba; const float* va;
    const float* W1; const float* b1; const float* W2; const float* b2;
    const float* W3; const float* b3;
    const int* t_ptr;
    float* out;
    float* hW;   // ws: [64][128]
    float* ex;   // ws: [5][8192]  e = exp(score), 0 if invalid
    int d[5];
};

__device__ __forceinline__ int load_t(const void* p) {
    unsigned w0 = *(const unsigned*)p;
    if (w0 < (unsigned)TSTEPS) return (int)w0;
    float f = __uint_as_float(w0);
    if (f >= 0.f && f < 256.f) return (int)f;
    return 8;
}

__device__ __forceinline__ float fast_tanh(float x) {
    float e = __expf(2.0f * x);
    return 1.0f - 2.0f / (e + 1.0f);
}

__device__ __forceinline__ int lower_bound(const int* a, int n, int v) {
    int lo = 0, hi = n;
    while (lo < hi) { int mid = (lo + hi) >> 1; if (a[mid] < v) lo = mid + 1; else hi = mid; }
    return lo;
}

// ---- kernel 0: hW[b][j] = ba[j] + h_ped[b] @ Wah[:,j]; ped/ego embeddings
__global__ __launch_bounds__(128) void k_prep(SP p) {
    const int b = blockIdx.x;
    const int j = threadIdx.x;
    const int t = load_t(p.t_ptr);
    float a = p.ba[j];
    const float* h = p.h_ped + b * DEMB;
    #pragma unroll
    for (int k = 0; k < DEMB; ++k) a += h[k] * p.Wah[k * DATT + j];
    p.hW[b * DATT + j] = a;

    if (j < DEMB) {
        const float* xp = p.x_ped + (size_t)(b * TSTEPS + t) * 4;
        float e = p.bp[j];
        #pragma unroll
        for (int k = 0; k < 4; ++k) e += xp[k] * p.Wp[k * DEMB + j];
        p.out[64 + b * 224 + j] = fmaxf(e, 0.f);
        const float* xe = p.x_ego + (size_t)(b * TSTEPS + t) * 4;
        float g = p.be[j];
        #pragma unroll
        for (int k = 0; k < 4; ++k) g += xe[k] * p.We[k * DEMB + j];
        p.out[64 + b * 224 + 192 + j] = fmaxf(g, 0.f);
    }
}

// ---- kernel 1: e[i] = valid ? exp(score_i) : 0.  8 lanes/object.
__global__ __launch_bounds__(256, 5) void k_score(SP p) {
    const int type = blockIdx.y;
    const int tid  = threadIdx.x;
    const int t    = load_t(p.t_ptr);
    const int d    = p.d[type];
    const float* __restrict__ x   = p.x[type];
    const int*   __restrict__ cls = p.cls[type];
    const int*   __restrict__ seg = p.seg[type];

    __shared__ __align__(16) float WaxT[DATT * DEMB];  // [j][k], linear
    __shared__ __align__(16) float W_s[7 * DEMB];
    __shared__ __align__(16) float b_s[DEMB];

    // coalesced stage of Wax transposed into WaxT
    for (int i = tid; i < DATT * DEMB; i += 256) {
        int k = i >> 7, j = i & 127;          // read Wax[k][j] coalesced
        WaxT[j * DEMB + k] = p.Wax[i];
    }
    for (int i = tid; i < d * DEMB; i += 256) W_s[i] = p.W[type][i];
    if (tid < DEMB) b_s[tid] = p.bias[type][tid];
    __syncthreads();

    const int i = blockIdx.x * OPB + (tid >> 3);
    const int q = tid & (LANES - 1);
    const bool valid = cls[i * TSTEPS + t] != -1;
    float e_val = 0.f;

    if (valid) {
        const int b = seg[i];
        float xv[7];
        const float* xr = x + (size_t)(i * TSTEPS + t) * d;
        for (int k = 0; k < d; ++k) xv[k] = xr[k];

        // emb chunks stored rotated by q: reg slot cc holds logical chunk (cc+q)&7
        float emb_r[DEMB];
        const float4* b4 = (const float4*)b_s;
        #pragma unroll
        for (int cc = 0; cc < 8; ++cc) {
            const int c = (cc + q) & 7;          // runtime LDS index: fine
            float4 a = b4[c];
            for (int k = 0; k < d; ++k) {
                const float4 w = *(const float4*)&W_s[k * DEMB + 4 * c];
                a.x += xv[k] * w.x; a.y += xv[k] * w.y;
                a.z += xv[k] * w.z; a.w += xv[k] * w.w;
            }
            emb_r[4*cc+0] = fmaxf(a.x, 0.f); emb_r[4*cc+1] = fmaxf(a.y, 0.f);
            emb_r[4*cc+2] = fmaxf(a.z, 0.f); emb_r[4*cc+3] = fmaxf(a.w, 0.f);
        }

        float sc = 0.f;
        const float4* hw4 = (const float4*)(p.hW + b * DATT + q * 16);
        const float4* va4 = (const float4*)(p.va + q * 16);
        #pragma unroll
        for (int w4 = 0; w4 < 4; ++w4) {
            const float4 hw = hw4[w4];
            const float4 vv = va4[w4];
            #pragma unroll
            for (int u = 0; u < 4; ++u) {
                const int j = q * 16 + w4 * 4 + u;
                const float* wrow = &WaxT[j * DEMB];
                float s0 = 0.f, s1 = 0.f, s2 = 0.f, s3 = 0.f;
                #pragma unroll
                for (int cc = 0; cc < 8; ++cc) {
                    const int c = (cc + q) & 7;   // banks 4c: disjoint across q
                    const float4 w = *(const float4*)&wrow[4 * c];
                    s0 += emb_r[4*cc+0] * w.x;
                    s1 += emb_r[4*cc+1] * w.y;
                    s2 += emb_r[4*cc+2] * w.z;
                    s3 += emb_r[4*cc+3] * w.w;
                }
                const float a = (&hw.x)[u] + ((s0 + s1) + (s2 + s3));
                sc += fast_tanh(a) * (&vv.x)[u];
            }
        }
        sc += __shfl_xor(sc, 1);
        sc += __shfl_xor(sc, 2);
        sc += __shfl_xor(sc, 4);
        e_val = __expf(sc);
    }
    if (q == 0) p.ex[type * NOBJ + i] = e_val;
}

// ---- kernel 2: per (type,segment): denom, probs, weighted feature sum
__global__ __launch_bounds__(256) void k_finish(SP p) {
    const int type = blockIdx.y;
    const int bseg = blockIdx.x;
    const int tid  = threadIdx.x;
    const int t    = load_t(p.t_ptr);
    const int d    = p.d[type];
    const float* __restrict__ x   = p.x[type];
    const int*   __restrict__ seg = p.seg[type];
    const float* __restrict__ ex  = p.ex + type * NOBJ;

    __shared__ __align__(16) float W_s[7 * DEMB];
    __shared__ __align__(16) float b_s[DEMB];
    __shared__ float sred[4];
    __shared__ float accred[4][DEMB];
    __shared__ float Sf_s;

    for (int i = tid; i < d * DEMB; i += 256) W_s[i] = p.W[type][i];
    if (tid < DEMB) b_s[tid] = p.bias[type][tid];
    const int lo = lower_bound(seg, NOBJ, bseg);
    const int hi = lower_bound(seg, NOBJ, bseg + 1);
    __syncthreads();

    // denom = sum e over segment
    float s = 0.f;
    for (int i = lo + tid; i < hi; i += 256) s += ex[i];
    #pragma unroll
    for (int off = 32; off; off >>= 1) s += __shfl_xor(s, off);
    const int wave = tid >> 6;
    if ((tid & 63) == 0) sred[wave] = s;
    __syncthreads();
    if (tid == 0) Sf_s = fmaxf(sred[0] + sred[1] + sred[2] + sred[3], 1e-30f);
    __syncthreads();
    const float inv = 1.0f / Sf_s;

    float acc[DEMB];
    #pragma unroll
    for (int j = 0; j < DEMB; ++j) acc[j] = 0.f;
    float* pout = p.out + 64 + BATCH * 224 + type * NOBJ;
    const float4* W4 = (const float4*)W_s;
    const float4* b4 = (const float4*)b_s;
    for (int i = lo + tid; i < hi; i += 256) {
        const float e = ex[i];
        const float pr = e * inv;
        pout[i] = pr;
        if (e > 0.f) {
            float xv[7];
            const float* xr = x + (size_t)(i * TSTEPS + t) * d;
            for (int k = 0; k < d; ++k) xv[k] = xr[k];
            #pragma unroll
            for (int j4 = 0; j4 < 8; ++j4) {
                float4 a = b4[j4];
                for (int k = 0; k < d; ++k) {
                    const float4 w = W4[k * 8 + j4];
                    a.x += xv[k]*w.x; a.y += xv[k]*w.y; a.z += xv[k]*w.z; a.w += xv[k]*w.w;
                }
                acc[4*j4+0] += pr * fmaxf(a.x, 0.f);
                acc[4*j4+1] += pr * fmaxf(a.y, 0.f);
                acc[4*j4+2] += pr * fmaxf(a.z, 0.f);
                acc[4*j4+3] += pr * fmaxf(a.w, 0.f);
            }
        }
    }
    #pragma unroll
    for (int j = 0; j < DEMB; ++j)
        #pragma unroll
        for (int off = 32; off; off >>= 1)
            acc[j] += __shfl_xor(acc[j], off);
    if ((tid & 63) == 0)
        for (int j = 0; j < DEMB; ++j) accred[wave][j] = acc[j];
    __syncthreads();
    if (tid < DEMB) {
        const float f = accred[0][tid] + accred[1][tid] + accred[2][tid] + accred[3][tid];
        p.out[64 + bseg * 224 + 32 * (1 + type) + tid] = f;
    }
}

// ---- kernel 3: classifier head
__global__ __launch_bounds__(256) void k_head(SP p) {
    const int tid = threadIdx.x;
    __shared__ __align__(16) float W1_s[224 * DEMB];
    __shared__ float W2_s[DEMB * DEMB];
    __shared__ float H1[BATCH][DEMB + 1];
    __shared__ float H2[BATCH][DEMB + 1];
    __shared__ float b1_s[DEMB], b2_s[DEMB], W3_s[DEMB];

    for (int i = tid; i < 224 * DEMB; i += 256) W1_s[i] = p.W1[i];
    for (int i = tid; i < DEMB * DEMB; i += 256) W2_s[i] = p.W2[i];
    if (tid < DEMB) { b1_s[tid] = p.b1[tid]; b2_s[tid] = p.b2[tid]; W3_s[tid] = p.W3[tid]; }
    __syncthreads();

    const float* feats = p.out + 64;
    for (int idx = tid; idx < BATCH * DEMB; idx += 256) {
        int b = idx >> 5, j = idx & 31;
        float a = b1_s[j];
        const float4* f4 = (const float4*)(feats + b * 224);
        #pragma unroll 8
        for (int k4 = 0; k4 < 56; ++k4) {
            float4 f = f4[k4];
            a += f.x * W1_s[(4*k4+0)*DEMB + j] + f.y * W1_s[(4*k4+1)*DEMB + j]
               + f.z * W1_s[(4*k4+2)*DEMB + j] + f.w * W1_s[(4*k4+3)*DEMB + j];
        }
        H1[b][j] = fmaxf(a, 0.f);
    }
    __syncthreads();
    for (int idx = tid; idx < BATCH * DEMB; idx += 256) {
        int b = idx >> 5, j = idx & 31;
        float a = b2_s[j];
        #pragma unroll
        for (int k = 0; k < DEMB; ++k) a += H1[b][k] * W2_s[k * DEMB + j];
        H2[b][j] = fmaxf(a, 0.f);
    }
    __syncthreads();
    if (tid < BATCH) {
        float a = p.b3[0];
        #pragma unroll
        for (int k = 0; k < DEMB; ++k) a += H2[tid][k] * W3_s[k];
        p.out[tid] = a;
    }
}

extern "C" void kernel_launch(void* const* d_in, const int* in_sizes, int n_in,
                              void* d_out, int out_size, void* d_ws, size_t ws_size,
                              hipStream_t stream) {
    (void)in_sizes; (void)n_in; (void)out_size; (void)ws_size;

    SP p;
    const int xi[5] = {3, 6, 9, 12, 15};
    const int wi[5] = {20, 22, 24, 26, 28};
    const int di[5] = {4, 6, 5, 7, 7};
    for (int tp = 0; tp < 5; ++tp) {
        p.x[tp]    = (const float*)d_in[xi[tp]];
        p.cls[tp]  = (const int*)d_in[xi[tp] + 1];
        p.seg[tp]  = (const int*)d_in[xi[tp] + 2];
        p.W[tp]    = (const float*)d_in[wi[tp]];
        p.bias[tp] = (const float*)d_in[wi[tp] + 1];
        p.d[tp]    = di[tp];
    }
    p.x_ped = (const float*)d_in[0];
    p.x_ego = (const float*)d_in[1];
    p.h_ped = (const float*)d_in[2];
    p.Wp = (const float*)d_in[18]; p.bp = (const float*)d_in[19];
    p.We = (const float*)d_in[30]; p.be = (const float*)d_in[31];
    p.Wax = (const float*)d_in[32]; p.Wah = (const float*)d_in[33];
    p.ba  = (const float*)d_in[34]; p.va  = (const float*)d_in[35];
    p.W1 = (const float*)d_in[36]; p.b1 = (const float*)d_in[37];
    p.W2 = (const float*)d_in[38]; p.b2 = (const float*)d_in[39];
    p.W3 = (const float*)d_in[40]; p.b3 = (const float*)d_in[41];
    p.t_ptr = (const int*)d_in[42];
    p.out = (float*)d_out;
    p.hW = (float*)d_ws;                                  // 32 KB
    p.ex = (float*)((char*)d_ws + BATCH * DATT * 4);      // 160 KB

    hipLaunchKernelGGL(k_prep,   dim3(BATCH),           dim3(DATT), 0, stream, p);
    hipLaunchKernelGGL(k_score,  dim3(NOBJ / OPB, 5),   dim3(256),  0, stream, p);
    hipLaunchKernelGGL(k_finish, dim3(BATCH, 5),        dim3(256),  0, stream, p);
    hipLaunchKernelGGL(k_head,   dim3(1),               dim3(256),  0, stream, p);
}